// Round 8
// baseline (257.621 us; speedup 1.0000x reference)
//
#include <hip/hip_runtime.h>

// Problem dims (fixed by setup_inputs)
#define BATCH 4
#define HH 128
#define WW 128
#define CC 128
#define BIN 64
#define NPIX (BATCH * HH * WW)   // 65536

typedef short bf16x8 __attribute__((ext_vector_type(8)));
typedef float f32x4 __attribute__((ext_vector_type(4)));

// round-to-nearest-even bf16 bits of f
__device__ __forceinline__ unsigned bf_hi(float f) {
    unsigned u = __float_as_uint(f);
    return (u + 0x7fffu + ((u >> 16) & 1u)) >> 16;
}
// A-operand split: per c, k' slots [4c..4c+3] = [xh, xh, xl, xl]
__device__ __forceinline__ uint2 split_aa(float f) {
    unsigned hb = bf_hi(f);
    float lo = f - __uint_as_float(hb << 16);
    unsigned lb = bf_hi(lo);
    return make_uint2(hb | (hb << 16), lb | (lb << 16));
}

// ---------------------------------------------------------------------------
// Kernel 0: pre-split W into bf16 [conv][d][k'=4c+slot], slots [wh,wl,wh,wl]
// (matches A's [xh,xh,xl,xl] -> full fp32 product). NOW PARKED IN d_ws:
// the fused kernel writes d_out while other blocks still read WS.
// ---------------------------------------------------------------------------
__global__ void presplit_w_kernel(const float* __restrict__ Wm,
                                  const float* __restrict__ Wr,
                                  unsigned short* __restrict__ WS) {
    const int t = blockIdx.x * 256 + threadIdx.x;   // 32768 total
    const int conv = t >> 14;
    const int d = (t >> 7) & 127;
    const int c = t & 127;
    const float* W = conv ? Wr : Wm;
    const float f = W[c * CC + d];
    const unsigned hb = bf_hi(f);
    const float lo = f - __uint_as_float(hb << 16);
    const unsigned lb = bf_hi(lo);
    const unsigned pk = hb | (lb << 16);            // [wh, wl]
    *(uint2*)(WS + ((size_t)conv * 128 + d) * 512 + c * 4) = make_uint2(pk, pk);
}

// ---------------------------------------------------------------------------
// FUSED kernel: per 8x8 tile -> Q[64x128] & K-halo[144x128] via split-bf16
// MFMA, then VALU 5x5 attention, all in LDS. 1024 blocks x 256 thr (4 waves),
// 157.5 KB dynamic LDS (1 block/CU).
//  LDS map:  KH fp32 [144 px][4 q x 36]      82,944 B  @ 0
//            QS fp32 [ 64 px][4 q x 36]      36,864 B  @ 82944
//            union { ASTG bf16 [208][72]     29,952 B
//                    VS  fp32 [144][4 x 18]  41,472 B } @ 119808
//  Layouts hand-checked conflict-free: quarter stride 36 fl (==4 mod 8) and
//  px stride 144 fl (==16 mod 32) tile all 32 banks per 8-lane b128 group.
//  GEMM: wave w owns d in [32w,32w+32); A-frags from ASTG rows (tile 0..63,
//  halo 64..207); B-frags from pre-split WS (L2-hot). C-layout scatter
//  col=lane&15,row=(lane>>4)*4+reg (validated R4-R7).
//  OOB: halo rows clamped at stage; invalid logits = 0 pre-softmax, weights
//  = 0 post-softmax == reference zero-padded extract_patches (validated R1+).
// ---------------------------------------------------------------------------
#define QROW 144        // floats per px row (4 quarters x 36)
#define KH_OFF 0
#define QS_OFF 82944
#define UN_OFF 119808
#define SMEM_BYTES 161280

__global__ __launch_bounds__(256, 1)
void fused_kernel(const float* __restrict__ main_in,
                  const float* __restrict__ ref_in,
                  const float* __restrict__ ref_value,
                  const unsigned short* __restrict__ Wsplit,
                  float* __restrict__ out) {
    extern __shared__ char smem[];
    float* KH = (float*)(smem + KH_OFF);
    float* QS = (float*)(smem + QS_OFF);
    unsigned short* ASTG = (unsigned short*)(smem + UN_OFF);
    float* VS = (float*)(smem + UN_OFF);

    const int t  = threadIdx.x;
    const int wv = t >> 6;
    const int l  = t & 63;
    const int lr = l & 15;
    const int lq = l >> 4;

    const int bx = blockIdx.x;
    const int bi = bx >> 8;
    const int ty = (bx >> 4) & 15;
    const int tx = bx & 15;
    const int h0 = ty * 8, w0 = tx * 8;
    const int gbase = bi * HH * WW;

    // ---- staging assignment: 832 float4 jobs (208 rows x 4 parts) ----
    const float* sptr[4];
    int srow[4], sprt[4];
    bool svld[4];
#pragma unroll
    for (int i = 0; i < 4; ++i) {
        const int s = i * 256 + t;
        svld[i] = (s < 832);
        const int row = (s >> 2) & 255;
        const int part = s & 3;
        srow[i] = row; sprt[i] = part;
        int gpix;
        const float* src;
        if (row < 64) {
            const int r = row >> 3, c = row & 7;
            gpix = gbase + (h0 + r) * WW + (w0 + c);
            src = main_in;
        } else {
            const int hp = (row - 64) % 144;
            const int py = hp / 12, pxx = hp - py * 12;
            int hh = h0 + py - 2;  hh = hh < 0 ? 0 : (hh > HH - 1 ? HH - 1 : hh);
            int ww = w0 + pxx - 2; ww = ww < 0 ? 0 : (ww > WW - 1 ? WW - 1 : ww);
            gpix = gbase + hh * WW + ww;
            src = ref_in;
        }
        sptr[i] = src + (size_t)gpix * CC + part * 4;
    }

    const unsigned short* WSm = Wsplit;                 // conv_main table
    const unsigned short* WSr = Wsplit + 128 * 512;     // conv_ref table

    f32x4 accQ[4][2] = {};
    f32x4 accK[9][2] = {};

    float4 pf[4];
#pragma unroll
    for (int i = 0; i < 4; ++i)
        pf[i] = svld[i] ? *(const float4*)(sptr[i]) : make_float4(0.f,0.f,0.f,0.f);

    for (int ch = 0; ch < 8; ++ch) {        // 16 c per chunk = 64 k'
        // write prefetched chunk to ASTG (split-bf16)
#pragma unroll
        for (int i = 0; i < 4; ++i) {
            if (svld[i]) {
                unsigned short* arow = &ASTG[srow[i] * 72 + sprt[i] * 16];
                uint2 a0 = split_aa(pf[i].x), a1 = split_aa(pf[i].y),
                      a2 = split_aa(pf[i].z), a3 = split_aa(pf[i].w);
                *(uint4*)(arow)     = make_uint4(a0.x, a0.y, a1.x, a1.y);
                *(uint4*)(arow + 8) = make_uint4(a2.x, a2.y, a3.x, a3.y);
            }
        }
        // prefetch next chunk (global, covered by MFMAs below)
        if (ch < 7) {
#pragma unroll
            for (int i = 0; i < 4; ++i)
                if (svld[i]) pf[i] = *(const float4*)(sptr[i] + (ch + 1) * 16);
        }
        __syncthreads();
#pragma unroll
        for (int ks = 0; ks < 2; ++ks) {
            // B-frags from global pre-split W (L2-hot)
            bf16x8 bQ[2], bK[2];
#pragma unroll
            for (int ni = 0; ni < 2; ++ni) {
                const size_t boff = (size_t)(wv * 32 + ni * 16 + lr) * 512
                                    + ch * 64 + ks * 32 + lq * 8;
                bQ[ni] = *(const bf16x8*)(WSm + boff);
                bK[ni] = *(const bf16x8*)(WSr + boff);
            }
            // A-frags from LDS
            bf16x8 aQ[4], aK[9];
#pragma unroll
            for (int mi = 0; mi < 4; ++mi)
                aQ[mi] = *(const bf16x8*)&ASTG[(mi * 16 + lr) * 72 + ks * 32 + lq * 8];
#pragma unroll
            for (int mi = 0; mi < 9; ++mi)
                aK[mi] = *(const bf16x8*)&ASTG[(64 + mi * 16 + lr) * 72 + ks * 32 + lq * 8];
#pragma unroll
            for (int mi = 0; mi < 4; ++mi)
#pragma unroll
                for (int ni = 0; ni < 2; ++ni)
                    accQ[mi][ni] = __builtin_amdgcn_mfma_f32_16x16x32_bf16(
                        aQ[mi], bQ[ni], accQ[mi][ni], 0, 0, 0);
#pragma unroll
            for (int mi = 0; mi < 9; ++mi)
#pragma unroll
                for (int ni = 0; ni < 2; ++ni)
                    accK[mi][ni] = __builtin_amdgcn_mfma_f32_16x16x32_bf16(
                        aK[mi], bK[ni], accK[mi][ni], 0, 0, 0);
        }
        __syncthreads();
    }

    // ---- epilogue scatter: C-layout col=lane&15, row=(lane>>4)*4+reg ----
    // d = wv*32 + ni*16 + lr -> quarter = wv, intra = ni*16 + lr
#pragma unroll
    for (int mi = 0; mi < 4; ++mi)
#pragma unroll
        for (int ni = 0; ni < 2; ++ni)
#pragma unroll
            for (int reg = 0; reg < 4; ++reg) {
                const int row = mi * 16 + lq * 4 + reg;
                QS[row * QROW + wv * 36 + ni * 16 + lr] = accQ[mi][ni][reg];
            }
#pragma unroll
    for (int mi = 0; mi < 9; ++mi)
#pragma unroll
        for (int ni = 0; ni < 2; ++ni)
#pragma unroll
            for (int reg = 0; reg < 4; ++reg) {
                const int row = mi * 16 + lq * 4 + reg;
                KH[row * QROW + wv * 36 + ni * 16 + lr] = accK[mi][ni][reg];
            }
    __syncthreads();

    // ---- attention: 4 thr/px, thread owns channel quarter cq (32 ch) ----
    const int px = t >> 2;          // local pixel 0..63
    const int cq = t & 3;           // quarter
    const int r = px >> 3, c = px & 7;
    const int pix = gbase + (h0 + r) * WW + (w0 + c);

    unsigned vm = 0;
#pragma unroll
    for (int dy = 0; dy < 5; ++dy)
#pragma unroll
        for (int dx = 0; dx < 5; ++dx) {
            const int hh = h0 + r + dy - 2, ww = w0 + c + dx - 2;
            if ((unsigned)hh < (unsigned)HH && (unsigned)ww < (unsigned)WW)
                vm |= 1u << (dy * 5 + dx);
        }

    // issue V-halo global loads now (9 float4/thread), land during logits
    float4 vld[9];
    int vslot[9];
#pragma unroll
    for (int i = 0; i < 9; ++i) {
        const int s = i * 256 + t;          // 0..2303
        const int hp = s >> 4;              // halo px 0..143
        const int f  = s & 15;              // float4 index in 64 bins
        const int py = hp / 12, pxx = hp - py * 12;
        int hh = h0 + py - 2;  hh = hh < 0 ? 0 : (hh > HH - 1 ? HH - 1 : hh);
        int ww = w0 + pxx - 2; ww = ww < 0 ? 0 : (ww > WW - 1 ? WW - 1 : ww);
        vld[i] = *(const float4*)(ref_value + (size_t)(gbase + hh * WW + ww) * BIN + f * 4);
        vslot[i] = hp * 72 + (f >> 2) * 18 + (f & 3) * 4;
    }

    // logits: this thread's 32 channels
    float lg[25];
    {
        float4 q4[8];
        const float* qb = QS + px * QROW + cq * 36;
#pragma unroll
        for (int g = 0; g < 8; ++g) q4[g] = *(const float4*)(qb + g * 4);
#pragma unroll
        for (int dy = 0; dy < 5; ++dy)
#pragma unroll
            for (int dx = 0; dx < 5; ++dx) {
                const int hp = (r + dy) * 12 + (c + dx);
                const float* kb = KH + hp * QROW + cq * 36;
                float part = 0.0f;
#pragma unroll
                for (int g = 0; g < 8; ++g) {
                    float4 kv = *(const float4*)(kb + g * 4);
                    part += q4[g].x * kv.x + q4[g].y * kv.y +
                            q4[g].z * kv.z + q4[g].w * kv.w;
                }
                lg[dy * 5 + dx] = part;
            }
    }

    // stash V-halo into VS (overwrites ASTG region; GEMM reads done)
#pragma unroll
    for (int i = 0; i < 9; ++i)
        *(float4*)(VS + vslot[i]) = vld[i];

    // merge quarters, mask, softmax (all 4 copies identical)
    {
#pragma unroll
        for (int kk = 0; kk < 25; ++kk) {
            lg[kk] += __shfl_xor(lg[kk], 1, 64);
            lg[kk] += __shfl_xor(lg[kk], 2, 64);
            if (!((vm >> kk) & 1)) lg[kk] = 0.0f;
        }
        float mx = lg[0];
#pragma unroll
        for (int kk = 1; kk < 25; ++kk) mx = fmaxf(mx, lg[kk]);
        float sum = 0.0f;
#pragma unroll
        for (int kk = 0; kk < 25; ++kk) {
            lg[kk] = __expf(lg[kk] - mx);
            sum += lg[kk];
        }
        const float inv = 1.0f / sum;
#pragma unroll
        for (int kk = 0; kk < 25; ++kk)
            lg[kk] = ((vm >> kk) & 1) ? lg[kk] * inv : 0.0f;
    }
    __syncthreads();    // VS complete

    // value mix: thread owns bin-quarter cq (16 bins = 4 float4)
    {
        float4 va[4];
#pragma unroll
        for (int g = 0; g < 4; ++g) va[g] = make_float4(0.f, 0.f, 0.f, 0.f);
#pragma unroll
        for (int dy = 0; dy < 5; ++dy)
#pragma unroll
            for (int dx = 0; dx < 5; ++dx) {
                const float wgt = lg[dy * 5 + dx];
                const float* vb = VS + ((r + dy) * 12 + (c + dx)) * 72 + cq * 18;
#pragma unroll
                for (int g = 0; g < 4; ++g) {
                    float4 v = *(const float4*)(vb + g * 4);
                    va[g].x += wgt * v.x; va[g].y += wgt * v.y;
                    va[g].z += wgt * v.z; va[g].w += wgt * v.w;
                }
            }
        float4* op = (float4*)(out + (size_t)pix * BIN + cq * 16);
#pragma unroll
        for (int g = 0; g < 4; ++g) op[g] = va[g];
    }
}

extern "C" void kernel_launch(void* const* d_in, const int* in_sizes, int n_in,
                              void* d_out, int out_size, void* d_ws, size_t ws_size,
                              hipStream_t stream) {
    const float* main_in   = (const float*)d_in[0];
    const float* ref_in    = (const float*)d_in[1];
    const float* ref_value = (const float*)d_in[2];
    const float* W_main    = (const float*)d_in[3];
    const float* W_ref     = (const float*)d_in[4];
    float* out = (float*)d_out;

    unsigned short* WS = (unsigned short*)d_ws;   // 256 KB pre-split W tables

    static int smem_set = 0;
    (void)smem_set;
    hipFuncSetAttribute((const void*)fused_kernel,
                        hipFuncAttributeMaxDynamicSharedMemorySize, SMEM_BYTES);

    presplit_w_kernel<<<128, 256, 0, stream>>>(W_main, W_ref, WS);

    // 1024 blocks (4 bi x 16 ty x 16 tx), 256 thr, 157.5 KB LDS
    fused_kernel<<<1024, 256, SMEM_BYTES, stream>>>(main_in, ref_in, ref_value,
                                                    WS, out);
}

// Round 9
// 243.794 us; speedup vs baseline: 1.0567x; 1.0567x over previous
//
#include <hip/hip_runtime.h>

// Problem dims (fixed by setup_inputs)
#define BATCH 4
#define HH 128
#define WW 128
#define CC 128
#define BIN 64
#define NPIX (BATCH * HH * WW)   // 65536

typedef short bf16x8 __attribute__((ext_vector_type(8)));
typedef float f32x4 __attribute__((ext_vector_type(4)));

union pack8 { uint4 u; bf16x8 b; };

// round-to-nearest-even bf16 bits of f
__device__ __forceinline__ unsigned bf_hi(float f) {
    unsigned u = __float_as_uint(f);
    return (u + 0x7fffu + ((u >> 16) & 1u)) >> 16;
}
// A-operand split: per c, k' slots [4c..4c+3] = [xh, xh, xl, xl]
__device__ __forceinline__ uint2 split_aa(float f) {
    unsigned hb = bf_hi(f);
    float lo = f - __uint_as_float(hb << 16);
    unsigned lb = bf_hi(lo);
    return make_uint2(hb | (hb << 16), lb | (lb << 16));
}

// ---------------------------------------------------------------------------
// Kernel 0: pre-split W into bf16 [conv][d][k'=4c+slot], slots [wh,wl,wh,wl]
// (matches A's [xh,xh,xl,xl] -> full fp32 product). Parked in d_out (256 KB);
// conv reads it; attn overwrites d_out strictly afterwards (stream-ordered).
// ---------------------------------------------------------------------------
__global__ void presplit_w_kernel(const float* __restrict__ Wm,
                                  const float* __restrict__ Wr,
                                  unsigned short* __restrict__ WS) {
    const int t = blockIdx.x * 256 + threadIdx.x;   // 32768 total
    const int conv = t >> 14;
    const int d = (t >> 7) & 127;
    const int c = t & 127;
    const float* W = conv ? Wr : Wm;
    const float f = W[c * CC + d];
    const unsigned hb = bf_hi(f);
    const float lo = f - __uint_as_float(hb << 16);
    const unsigned lb = bf_hi(lo);
    const unsigned pk = hb | (lb << 16);            // [wh, wl]
    *(uint2*)(WS + ((size_t)conv * 128 + d) * 512 + c * 4) = make_uint2(pk, pk);
}

// ---------------------------------------------------------------------------
// Kernel 1: 1x1 conv via split-bf16 MFMA -- NO LDS, NO BARRIERS.
// Each wave independently computes a 32px x 64d output block. A-frags are
// built per-lane in registers: lane l loads X[pxb + mi*16 + (l&15)] floats
// [8ks+2q, 8ks+2q+1] (q = l>>4) and splits to [h,h,l,l,h,h,l,l] -- exactly
// the A[m=l&15][k=q*8+j] fragment layout (validated R4-R8 via LDS path).
// B-frags from pre-split WS (L2-hot, 256 KB). 2048 blocks = 8/CU: latency
// hidden purely by TLP. C-scatter col=lane&15,row=(lane>>4)*4+reg (validated).
// ---------------------------------------------------------------------------
__global__ __launch_bounds__(256, 4)
void conv_mfma_kernel(const float* __restrict__ Xm, const float* __restrict__ Xr,
                      const unsigned short* __restrict__ Wsplit,
                      float* __restrict__ Ym, float* __restrict__ Yr) {
    const float* __restrict__ X = blockIdx.y ? Xr : Xm;
    const unsigned short* __restrict__ WS = Wsplit + (size_t)blockIdx.y * 128 * 512;
    float* __restrict__ Y = blockIdx.y ? Yr : Ym;

    const int t  = threadIdx.x;
    const int wv = t >> 6;
    const int l  = t & 63;
    const int lr = l & 15;
    const int lq = l >> 4;
    const int pxb = blockIdx.x * 64 + (wv & 1) * 32;   // wave's 32-px block
    const int dnb = (wv >> 1) * 64;                    // wave's 64-d block

    const float* xrow0 = X + (size_t)(pxb + lr) * CC + 2 * lq;
    const float* xrow1 = X + (size_t)(pxb + 16 + lr) * CC + 2 * lq;
    const unsigned short* wsb = WS + (size_t)(dnb + lr) * 512 + lq * 8;

    f32x4 acc[2][4] = {};

    float2 x0 = *(const float2*)(xrow0);
    float2 x1 = *(const float2*)(xrow1);

#pragma unroll 2
    for (int ks = 0; ks < 16; ++ks) {
        // build A-frags in registers from the prefetched float2s
        pack8 a0, a1;
        {
            uint2 s0 = split_aa(x0.x), s1 = split_aa(x0.y);
            a0.u = make_uint4(s0.x, s0.y, s1.x, s1.y);
            uint2 s2 = split_aa(x1.x), s3 = split_aa(x1.y);
            a1.u = make_uint4(s2.x, s2.y, s3.x, s3.y);
        }
        // prefetch next ks (lands during the 8 MFMAs)
        if (ks < 15) {
            x0 = *(const float2*)(xrow0 + 8 * (ks + 1));
            x1 = *(const float2*)(xrow1 + 8 * (ks + 1));
        }
        // B-frags from L2-hot pre-split W
        bf16x8 bfr[4];
#pragma unroll
        for (int ni = 0; ni < 4; ++ni)
            bfr[ni] = *(const bf16x8*)(wsb + ni * 8192 + ks * 32);
#pragma unroll
        for (int ni = 0; ni < 4; ++ni) {
            acc[0][ni] = __builtin_amdgcn_mfma_f32_16x16x32_bf16(
                a0.b, bfr[ni], acc[0][ni], 0, 0, 0);
            acc[1][ni] = __builtin_amdgcn_mfma_f32_16x16x32_bf16(
                a1.b, bfr[ni], acc[1][ni], 0, 0, 0);
        }
    }

    // epilogue: C/D layout col=lane&15, row=(lane>>4)*4+reg
#pragma unroll
    for (int mi = 0; mi < 2; ++mi)
#pragma unroll
        for (int ni = 0; ni < 4; ++ni)
#pragma unroll
            for (int reg = 0; reg < 4; ++reg) {
                const int row = pxb + mi * 16 + lq * 4 + reg;
                Y[(size_t)row * CC + dnb + ni * 16 + lr] = acc[mi][ni][reg];
            }
}

// ---------------------------------------------------------------------------
// Kernel 2: local 5x5 attention, 2 thr/px (channel halves), 8x8 tiles,
// double-buffered DMA staging. 1024 blocks x 128 thr, LDS 2 x 20.5 KB
// -> exactly 4 blocks/CU resident (single full-machine pass, 8 waves/CU).
// Layout [half][g][py][13]: half-stride 628 fl4 (==4 mod 8) puts half0 on
// banks 0-15 and half1 on banks 16-31 per 8-lane b128 service group -> all
// 25 neighbor reads conflict-free for every (dy,dx) (verified arithmetic).
// Phase p+1's DMA is issued right after phase p's drain barrier -> a full
// phase (~2K cyc) of DS+VALU covers it. Staging addresses precomputed once
// (packed gpix|g<<16 in 10 VGPRs) -- no divides in the loop.
// OOB: staged addrs clamped (never read); invalid logits = 0 pre-softmax,
// weights = 0 post-softmax == reference zero-padding (validated R1+).
// ---------------------------------------------------------------------------
#define HGRP 156          // 12 rows * 13 (padded from 12)
#define HSTR 628          // half-region stride: 4*156 + 4  (== 4 mod 8)

__global__ __launch_bounds__(128, 4)
void attn_kernel(const float* __restrict__ qm, const float* __restrict__ kr,
                 const float* __restrict__ vv, float* __restrict__ out) {
    __shared__ float4 KS[2][1280];   // 40 KB

    const int t   = threadIdx.x;
    const int wid = t >> 6;
    const int ln  = t & 63;
    const int bx  = blockIdx.x;
    const int bi  = bx >> 8;
    const int ty  = (bx >> 4) & 15;
    const int tx  = bx & 15;
    const int h0 = ty * 8, w0 = tx * 8;

    const int px   = t >> 1;      // local px 0..63
    const int half = t & 1;       // channel half
    const int r = px >> 3, c = px & 7;
    const int gbase = bi * HH * WW;
    const int pix = gbase + (h0 + r) * WW + (w0 + c);

    // 25-bit validity mask
    unsigned vm = 0;
#pragma unroll
    for (int dy = 0; dy < 5; ++dy)
#pragma unroll
        for (int dx = 0; dx < 5; ++dx) {
            const int hh = h0 + r + dy - 2, ww = w0 + c + dx - 2;
            if ((unsigned)hh < (unsigned)HH && (unsigned)ww < (unsigned)WW)
                vm |= 1u << (dy * 5 + dx);
        }

    // precompute the 10 staging jobs once: pack gpix (16b) | g (<<16)
    unsigned spack[10];
#pragma unroll
    for (int i = 0; i < 10; ++i) {
        int s = i * 128 + wid * 64 + ln;
        if (s > 1255) s = 1255;
        const int hr = (s >= HSTR) ? 1 : 0;
        int rem = s - hr * HSTR;
        if (rem > 623) rem = 623;
        const int g    = hr * 4 + rem / HGRP;
        const int rem2 = rem % HGRP;
        const int py   = rem2 / 13;
        int pxx = rem2 - py * 13;
        if (pxx > 11) pxx = 11;
        int hh = h0 + py - 2;  hh = hh < 0 ? 0 : (hh > HH - 1 ? HH - 1 : hh);
        int ww = w0 + pxx - 2; ww = ww < 0 ? 0 : (ww > WW - 1 ? WW - 1 : ww);
        spack[i] = (unsigned)(gbase + hh * WW + ww) | ((unsigned)g << 16);
    }

    auto stage = [&](int phase, int buf) {
        const float* src = (phase < 4) ? kr : vv;
        const int ld  = (phase < 4) ? CC : BIN;
        const int chb = (phase < 4) ? phase * 32 : (phase - 4) * 32;
#pragma unroll
        for (int i = 0; i < 10; ++i) {
            const unsigned u = spack[i];
            const float* gp = src + (size_t)(u & 0xFFFFu) * ld + chb + (u >> 16) * 4;
            __builtin_amdgcn_global_load_lds(
                (const __attribute__((address_space(1))) void*)gp,
                (__attribute__((address_space(3))) void*)&KS[buf][i * 128 + wid * 64],
                16, 0, 0);
        }
    };

    float lg[25];
#pragma unroll
    for (int i = 0; i < 25; ++i) lg[i] = 0.0f;

    stage(0, 0);

    const float4* qp = (const float4*)(qm + (size_t)pix * CC + half * 16);
    float4 qn[4];
#pragma unroll
    for (int g = 0; g < 4; ++g) qn[g] = qp[g];   // Q for phase 0 (covers DMA 0)

    // ---- 4 logit phases (32 ch each; this thread's half = 16 ch) ----
    for (int ph = 0; ph < 4; ++ph) {
        __syncthreads();                 // drains DMA(ph)
        stage(ph + 1, (ph + 1) & 1);     // covered by compute below
        float4 q4[4];
#pragma unroll
        for (int g = 0; g < 4; ++g) q4[g] = qn[g];
        if (ph < 3) {
#pragma unroll
            for (int g = 0; g < 4; ++g) qn[g] = qp[(ph + 1) * 8 + g];
        }
        const float4* B = KS[ph & 1] + half * HSTR;
#pragma unroll
        for (int dy = 0; dy < 5; ++dy)
#pragma unroll
            for (int dx = 0; dx < 5; ++dx) {
                const int hp = (r + dy) * 13 + (c + dx);
                float part = 0.0f;
#pragma unroll
                for (int gi = 0; gi < 4; ++gi) {
                    float4 kv = B[gi * HGRP + hp];
                    part += q4[gi].x * kv.x + q4[gi].y * kv.y +
                            q4[gi].z * kv.z + q4[gi].w * kv.w;
                }
                lg[dy * 5 + dx] += part;
            }
    }

    // ---- merge halves, mask, softmax (overlaps DMA of v-chunk 0) ----
    {
#pragma unroll
        for (int kk = 0; kk < 25; ++kk) {
            lg[kk] += __shfl_xor(lg[kk], 1, 64);     // t ^ 1 = other half
            if (!((vm >> kk) & 1)) lg[kk] = 0.0f;    // zero-pad logit
        }
        float mx = lg[0];
#pragma unroll
        for (int kk = 1; kk < 25; ++kk) mx = fmaxf(mx, lg[kk]);
        float sum = 0.0f;
#pragma unroll
        for (int kk = 0; kk < 25; ++kk) {
            lg[kk] = __expf(lg[kk] - mx);
            sum += lg[kk];
        }
        const float inv = 1.0f / sum;
#pragma unroll
        for (int kk = 0; kk < 25; ++kk)
            lg[kk] = ((vm >> kk) & 1) ? lg[kk] * inv : 0.0f;
    }

    // ---- 2 value phases (32 bins each; this thread's half = 16 bins) ----
    for (int ph = 4; ph < 6; ++ph) {
        __syncthreads();                 // drains DMA(ph)
        if (ph < 5) stage(ph + 1, (ph + 1) & 1);
        const float4* B = KS[ph & 1] + half * HSTR;
        float4 va[4];
#pragma unroll
        for (int gi = 0; gi < 4; ++gi) va[gi] = make_float4(0.f, 0.f, 0.f, 0.f);
#pragma unroll
        for (int dy = 0; dy < 5; ++dy)
#pragma unroll
            for (int dx = 0; dx < 5; ++dx) {
                const float wgt = lg[dy * 5 + dx];
                const int hp = (r + dy) * 13 + (c + dx);
#pragma unroll
                for (int gi = 0; gi < 4; ++gi) {
                    float4 v = B[gi * HGRP + hp];
                    va[gi].x += wgt * v.x; va[gi].y += wgt * v.y;
                    va[gi].z += wgt * v.z; va[gi].w += wgt * v.w;
                }
            }
        float4* op = (float4*)(out + (size_t)pix * BIN + (ph - 4) * 32 + half * 16);
#pragma unroll
        for (int gi = 0; gi < 4; ++gi) op[gi] = va[gi];
    }
}

extern "C" void kernel_launch(void* const* d_in, const int* in_sizes, int n_in,
                              void* d_out, int out_size, void* d_ws, size_t ws_size,
                              hipStream_t stream) {
    const float* main_in   = (const float*)d_in[0];
    const float* ref_in    = (const float*)d_in[1];
    const float* ref_value = (const float*)d_in[2];
    const float* W_main    = (const float*)d_in[3];
    const float* W_ref     = (const float*)d_in[4];
    float* out = (float*)d_out;

    float* conv_main = (float*)d_ws;                       // 32 MB
    float* conv_ref  = conv_main + (size_t)NPIX * CC;      // 32 MB
    // pre-split W parked in d_out (256 KB); conv reads it, attn overwrites
    // d_out strictly afterwards (stream-ordered) -- proven safe R4-R7.
    unsigned short* WS = (unsigned short*)d_out;

    presplit_w_kernel<<<128, 256, 0, stream>>>(W_main, W_ref, WS);

    // 1024 x 2 blocks = 2048 = 8/CU; no LDS, no barriers
    dim3 gconv(NPIX / 64, 2);
    conv_mfma_kernel<<<gconv, 256, 0, stream>>>(main_in, ref_in, WS,
                                                conv_main, conv_ref);

    // 1024 blocks (4 bi x 16 ty x 16 tx), 128 thr, 40 KB LDS = 4 blocks/CU
    attn_kernel<<<1024, 128, 0, stream>>>(conv_main, conv_ref, ref_value, out);
}